// Round 1
// baseline (469.964 us; speedup 1.0000x reference)
//
#include <hip/hip_runtime.h>
#include <cmath>

#define NB 512
#define NT 200
#define NIN 88
#define NH 60
#define NZ 100

// One block per batch element. 128 threads = 2 waves.
// Phase A: wave 0 runs the 200-step ReLU RNN, scattering h into h_rev (LDS)
//          at the per-sequence reversed position.
// Phase B: both waves run the 200-step combiner; wave0 lanes<60 compute
//          h_comb, lanes<50 of each wave own one z/loc/scale output pair half.
__global__ __launch_bounds__(128, 1)
void encoder_kernel(const float* __restrict__ xrev,    // [B][T][IN]
                    const int*   __restrict__ seqlen,  // [B]
                    const float* __restrict__ eps,     // [T][B][Z]
                    const float* __restrict__ W_ih,    // [H][IN]
                    const float* __restrict__ W_hh,    // [H][H]
                    const float* __restrict__ b_ih,    // [H]
                    const float* __restrict__ b_hh,    // [H]
                    const float* __restrict__ h0,      // [H]
                    const float* __restrict__ zq0,     // [Z]
                    const float* __restrict__ W_zh,    // [H][Z]
                    const float* __restrict__ b_zh,    // [H]
                    const float* __restrict__ W_hl,    // [Z][H]
                    const float* __restrict__ b_hl,    // [Z]
                    const float* __restrict__ W_hs,    // [Z][H]
                    const float* __restrict__ b_hs,    // [Z]
                    float* __restrict__ out)           // 3 x [B][T][Z]
{
    __shared__ __align__(16) float h_rev[NT][NH];  // 48000 B
    __shared__ __align__(16) float xbuf[NIN];
    __shared__ __align__(16) float hbuf[NH];
    __shared__ __align__(16) float zbuf[NZ];
    __shared__ __align__(16) float hcomb[NH];

    const int b    = blockIdx.x;
    const int tid  = threadIdx.x;
    const int wave = tid >> 6;
    const int lane = tid & 63;
    const int sl   = seqlen[b];

    // zero the reversed-RNN buffer (covers the zero-padded tail t >= sl)
    for (int i = tid; i < NT * NH; i += 128) (&h_rev[0][0])[i] = 0.0f;
    __syncthreads();

    // ---------------- Phase A: ReLU RNN (wave 0 only) ----------------
    if (wave == 0) {
        float wih[NIN], whh[NH];
        float bias = 0.0f;
        if (lane < NH) {
            const float4* p = reinterpret_cast<const float4*>(W_ih + lane * NIN);
#pragma unroll
            for (int k = 0; k < NIN / 4; ++k) {
                float4 v = p[k];
                wih[4*k+0] = v.x; wih[4*k+1] = v.y; wih[4*k+2] = v.z; wih[4*k+3] = v.w;
            }
            const float4* q = reinterpret_cast<const float4*>(W_hh + lane * NH);
#pragma unroll
            for (int k = 0; k < NH / 4; ++k) {
                float4 v = q[k];
                whh[4*k+0] = v.x; whh[4*k+1] = v.y; whh[4*k+2] = v.z; whh[4*k+3] = v.w;
            }
            bias = b_ih[lane] + b_hh[lane];
            hbuf[lane] = h0[lane];
        } else {
#pragma unroll
            for (int k = 0; k < NIN; ++k) wih[k] = 0.0f;
#pragma unroll
            for (int k = 0; k < NH; ++k) whh[k] = 0.0f;
        }

        const float* xb = xrev + (size_t)b * NT * NIN;
        // software prefetch of x_t (one step ahead)
        float xa = xb[lane];
        float xc = (lane < NIN - 64) ? xb[64 + lane] : 0.0f;

        for (int t = 0; t < NT; ++t) {
            xbuf[lane] = xa;
            if (lane < NIN - 64) xbuf[64 + lane] = xc;
            if (t + 1 < NT) {
                xa = xb[(size_t)(t + 1) * NIN + lane];
                xc = (lane < NIN - 64) ? xb[(size_t)(t + 1) * NIN + 64 + lane] : 0.0f;
            }
            float a0 = 0.f, a1 = 0.f, a2 = 0.f, a3 = 0.f;
            const float4* x4 = reinterpret_cast<const float4*>(xbuf);
#pragma unroll
            for (int k = 0; k < NIN / 4; ++k) {
                float4 v = x4[k];
                a0 += v.x * wih[4*k+0]; a1 += v.y * wih[4*k+1];
                a2 += v.z * wih[4*k+2]; a3 += v.w * wih[4*k+3];
            }
            const float4* h4 = reinterpret_cast<const float4*>(hbuf);
#pragma unroll
            for (int k = 0; k < NH / 4; ++k) {
                float4 v = h4[k];
                a0 += v.x * whh[4*k+0]; a1 += v.y * whh[4*k+1];
                a2 += v.z * whh[4*k+2]; a3 += v.w * whh[4*k+3];
            }
            float hn = fmaxf((a0 + a1) + (a2 + a3) + bias, 0.0f);
            if (lane < NH) {
                hbuf[lane] = hn;                       // in-order LDS: safe after reads
                if (t < sl) h_rev[sl - 1 - t][lane] = hn;
            }
        }
    }
    __syncthreads();

    // ---------------- Phase B: combiner (both waves) ----------------
    const int o = 50 * wave + lane;  // valid when lane < 50

    float wzr[NZ];
    float bz = 0.0f;
    if (wave == 0 && lane < NH) {
        const float4* p = reinterpret_cast<const float4*>(W_zh + lane * NZ);
#pragma unroll
        for (int k = 0; k < NZ / 4; ++k) {
            float4 v = p[k];
            wzr[4*k+0] = v.x; wzr[4*k+1] = v.y; wzr[4*k+2] = v.z; wzr[4*k+3] = v.w;
        }
        bz = b_zh[lane];
    } else {
#pragma unroll
        for (int k = 0; k < NZ; ++k) wzr[k] = 0.0f;
    }

    float wl[NH], ws_[NH];
    float bl = 0.0f, bs = 0.0f;
    if (lane < 50) {
        const float4* p = reinterpret_cast<const float4*>(W_hl + o * NH);
        const float4* q = reinterpret_cast<const float4*>(W_hs + o * NH);
#pragma unroll
        for (int k = 0; k < NH / 4; ++k) {
            float4 v = p[k];
            wl[4*k+0] = v.x; wl[4*k+1] = v.y; wl[4*k+2] = v.z; wl[4*k+3] = v.w;
            float4 u = q[k];
            ws_[4*k+0] = u.x; ws_[4*k+1] = u.y; ws_[4*k+2] = u.z; ws_[4*k+3] = u.w;
        }
        bl = b_hl[o];
        bs = b_hs[o];
        zbuf[o] = zq0[o];
    } else {
#pragma unroll
        for (int k = 0; k < NH; ++k) { wl[k] = 0.0f; ws_[k] = 0.0f; }
    }
    __syncthreads();

    float* out_z = out;
    float* out_l = out + (size_t)NB * NT * NZ;
    float* out_s = out + (size_t)2 * NB * NT * NZ;
    const float* epsb = eps + (size_t)b * NZ;

    float e_cur = (lane < 50) ? epsb[o] : 0.0f;  // eps[t=0][b][o]

    for (int t = 0; t < NT; ++t) {
        if (wave == 0) {
            float a0 = 0.f, a1 = 0.f, a2 = 0.f, a3 = 0.f;
            const float4* z4 = reinterpret_cast<const float4*>(zbuf);
#pragma unroll
            for (int k = 0; k < NZ / 4; ++k) {
                float4 v = z4[k];
                a0 += v.x * wzr[4*k+0]; a1 += v.y * wzr[4*k+1];
                a2 += v.z * wzr[4*k+2]; a3 += v.w * wzr[4*k+3];
            }
            if (lane < NH) {
                float a = (a0 + a1) + (a2 + a3) + bz;
                hcomb[lane] = 0.5f * (tanhf(a) + h_rev[t][lane]);
            }
        }
        __syncthreads();  // hcomb ready; also separates zbuf read (above) from write (below)

        float e_nxt = 0.0f;
        if (t + 1 < NT && lane < 50) e_nxt = epsb[(size_t)(t + 1) * NB * NZ + o];

        if (lane < 50) {
            float c0 = 0.f, c1 = 0.f, c2 = 0.f, c3 = 0.f;
            float d0 = 0.f, d1 = 0.f, d2 = 0.f, d3 = 0.f;
            const float4* h4 = reinterpret_cast<const float4*>(hcomb);
#pragma unroll
            for (int k = 0; k < NH / 4; ++k) {
                float4 v = h4[k];
                c0 += v.x * wl[4*k+0];  c1 += v.y * wl[4*k+1];
                c2 += v.z * wl[4*k+2];  c3 += v.w * wl[4*k+3];
                d0 += v.x * ws_[4*k+0]; d1 += v.y * ws_[4*k+1];
                d2 += v.z * ws_[4*k+2]; d3 += v.w * ws_[4*k+3];
            }
            float loc = (c0 + c1) + (c2 + c3) + bl;
            float ps  = (d0 + d1) + (d2 + d3) + bs;
            float sc  = fmaxf(ps, 0.0f) + log1pf(expf(-fabsf(ps)));  // stable softplus
            float zv  = loc + sc * e_cur;
            size_t oi = ((size_t)b * NT + t) * NZ + o;
            out_z[oi] = zv;
            out_l[oi] = loc;
            out_s[oi] = sc;
            zbuf[o] = zv;
        }
        e_cur = e_nxt;
        __syncthreads();  // zbuf ready for next step's phase 1
    }
}

extern "C" void kernel_launch(void* const* d_in, const int* in_sizes, int n_in,
                              void* d_out, int out_size, void* d_ws, size_t ws_size,
                              hipStream_t stream) {
    const float* xrev   = (const float*)d_in[1];
    const int*   seqlen = (const int*)  d_in[3];
    const float* eps    = (const float*)d_in[4];
    const float* W_ih   = (const float*)d_in[5];
    const float* W_hh   = (const float*)d_in[6];
    const float* b_ih   = (const float*)d_in[7];
    const float* b_hh   = (const float*)d_in[8];
    const float* h0     = (const float*)d_in[9];
    const float* zq0    = (const float*)d_in[10];
    const float* W_zh   = (const float*)d_in[11];
    const float* b_zh   = (const float*)d_in[12];
    const float* W_hl   = (const float*)d_in[13];
    const float* b_hl   = (const float*)d_in[14];
    const float* W_hs   = (const float*)d_in[15];
    const float* b_hs   = (const float*)d_in[16];
    float* out = (float*)d_out;

    encoder_kernel<<<NB, 128, 0, stream>>>(xrev, seqlen, eps,
                                           W_ih, W_hh, b_ih, b_hh, h0, zq0,
                                           W_zh, b_zh, W_hl, b_hl, W_hs, b_hs,
                                           out);
}